// Round 1
// baseline (417.955 us; speedup 1.0000x reference)
//
#include <hip/hip_runtime.h>
#include <hip/hip_bf16.h>

// BaseTimeAttention: out = ((softmax(rope(xWq)·rope(xWk)^T/sqrt(d)))·(xWv)) @ Wo^T
// bf16 MFMA everywhere (no fp32 MFMA on CDNA4), fp32 accum + fp32 softmax.
// d_ws layout (bf16 elems): xb/aob(8.4M) | qb(8.4M) | kb(8.4M) | vtb(8.4M) | wslot(4.2M) = 72MB

typedef __attribute__((ext_vector_type(8))) short short8;
typedef __attribute__((ext_vector_type(4))) float f32x4;
typedef __attribute__((ext_vector_type(4))) unsigned short us4;

__device__ __forceinline__ void gll16(const void* g, void* l) {
  __builtin_amdgcn_global_load_lds((const __attribute__((address_space(1))) void*)g,
                                   (__attribute__((address_space(3))) void*)l, 16, 0, 0);
}

__device__ __forceinline__ unsigned short f2bf(float f) {
  __hip_bfloat16 h = __float2bfloat16(f);
  return *reinterpret_cast<unsigned short*>(&h);
}

__global__ __launch_bounds__(256) void cast_f32_bf16(const float* __restrict__ in,
                                                     __hip_bfloat16* __restrict__ out, int n4) {
  int i = blockIdx.x * 256 + threadIdx.x;
  if (i >= n4) return;
  const float4 v = reinterpret_cast<const float4*>(in)[i];
  us4 o;
  o[0] = f2bf(v.x); o[1] = f2bf(v.y); o[2] = f2bf(v.z); o[3] = f2bf(v.w);
  *reinterpret_cast<us4*>(out + (size_t)i * 4) = o;
}

// C = A(MxK) * Bt(NxK)^T, 128x128 tile, BK=64, 4 waves (2x2 of 64x64).
// LDS tiles [128][64] bf16, XOR-swizzled: phys 16B-chunk = logical ^ (row&7).
// MODE 0: bf16 row-major. MODE 1: f32 row-major. MODE 2: V^T per (b,h) -> Cout[bh][d][kv].
template <int MODE>
__global__ __launch_bounds__(256) void gemm_bt(const __hip_bfloat16* __restrict__ A,
                                               const __hip_bfloat16* __restrict__ Bt,
                                               void* __restrict__ Cout,
                                               int M, int N, int K) {
  __shared__ char As[16384];
  __shared__ char Bs[16384];
  const int tid = threadIdx.x;
  const int lane = tid & 63, wid = tid >> 6;
  const int l15 = lane & 15, l4 = lane >> 4;
  const int row0 = blockIdx.x * 128, col0 = blockIdx.y * 128;
  const int wm = (wid >> 1) * 64, wn = (wid & 1) * 64;

  f32x4 acc[4][4] = {};

  const int rs = lane >> 3;       // row within 1KB staging chunk (8 rows x 128B)
  const int cs = lane & 7;        // 16B chunk within row
  const int cg = cs ^ rs;         // pre-swizzled global source chunk
  const char* Ab = (const char*)A;
  const char* Bb = (const char*)Bt;
  const size_t Kb = (size_t)K * 2;

  for (int k0 = 0; k0 < K; k0 += 64) {
#pragma unroll
    for (int c = 0; c < 4; ++c) {
      const int cid = wid * 4 + c;
      const int r = cid * 8 + rs;
      gll16(Ab + (size_t)(row0 + r) * Kb + (size_t)k0 * 2 + cg * 16, As + cid * 1024);
      gll16(Bb + (size_t)(col0 + r) * Kb + (size_t)k0 * 2 + cg * 16, Bs + cid * 1024);
    }
    __syncthreads();
#pragma unroll
    for (int kc = 0; kc < 2; ++kc) {
      short8 a[4], b[4];
#pragma unroll
      for (int i = 0; i < 4; ++i) {
        const int ra = wm + i * 16 + l15;
        a[i] = *(const short8*)(As + ra * 128 + (((kc * 4 + l4) ^ (ra & 7)) * 16));
        const int rb = wn + i * 16 + l15;
        b[i] = *(const short8*)(Bs + rb * 128 + (((kc * 4 + l4) ^ (rb & 7)) * 16));
      }
#pragma unroll
      for (int i = 0; i < 4; ++i)
#pragma unroll
        for (int j = 0; j < 4; ++j)
          acc[i][j] = __builtin_amdgcn_mfma_f32_16x16x32_bf16(a[i], b[j], acc[i][j], 0, 0, 0);
    }
    __syncthreads();
  }

  if (MODE == 2) {
    // C layout: col = lane&15, row = (lane>>4)*4 + reg -> 4 consecutive kv per lane: pack 8B.
    __hip_bfloat16* vt = (__hip_bfloat16*)Cout;
#pragma unroll
    for (int i = 0; i < 4; ++i) {
      const int gm = row0 + wm + i * 16 + l4 * 4;   // global row = b*2048 + kv
      const int bb = gm >> 11, kv = gm & 2047;
#pragma unroll
      for (int j = 0; j < 4; ++j) {
        const int gn = col0 + wn + j * 16 + l15;    // global col = h*128 + d
        const int h = gn >> 7, d = gn & 127;
        us4 o;
        o[0] = f2bf(acc[i][j][0]); o[1] = f2bf(acc[i][j][1]);
        o[2] = f2bf(acc[i][j][2]); o[3] = f2bf(acc[i][j][3]);
        *reinterpret_cast<us4*>(vt + ((size_t)((bb * 16 + h) * 128 + d) * 2048 + kv)) = o;
      }
    }
  } else {
#pragma unroll
    for (int i = 0; i < 4; ++i)
#pragma unroll
      for (int j = 0; j < 4; ++j) {
        const int gn = col0 + wn + j * 16 + l15;
#pragma unroll
        for (int r = 0; r < 4; ++r) {
          const int gm = row0 + wm + i * 16 + l4 * 4 + r;
          if (MODE == 0)
            ((__hip_bfloat16*)Cout)[(size_t)gm * N + gn] = __float2bfloat16(acc[i][j][r]);
          else
            ((float*)Cout)[(size_t)gm * N + gn] = acc[i][j][r];
        }
      }
  }
}

// RoPE in place on q and k. t -> (tensor, row, h, i); rotate (i, i+64) within each head.
__global__ __launch_bounds__(256) void rope_k(__hip_bfloat16* __restrict__ q,
                                              __hip_bfloat16* __restrict__ k) {
  const int tid = blockIdx.x * 256 + threadIdx.x;
  const int PT = 4096 * 16 * 64;
  __hip_bfloat16* p = (tid < PT) ? q : k;
  const int t = (tid < PT) ? tid : tid - PT;
  const int i = t & 63;
  const int h = (t >> 6) & 15;
  const int row = t >> 10;
  const int pos = row & 2047;
  const float invf = exp2f((float)i * -0.20762050593046f);  // 10000^(-i/64)
  const float fr = (float)pos * invf;
  float sv, cv;
  sincosf(fr, &sv, &cv);
  const size_t base = (size_t)row * 2048 + h * 128 + i;
  const float x1 = __bfloat162float(p[base]);
  const float x2 = __bfloat162float(p[base + 64]);
  p[base]      = __float2bfloat16(x1 * cv - x2 * sv);
  p[base + 64] = __float2bfloat16(x1 * sv + x2 * cv);
}

// Flash attention: grid.x = 512 (16 q-tiles x 32 bh). 4 waves x 32 q-rows, KV tile 64.
// Q in regs; K [64][128] and V^T [128][64] staged via swizzled global_load_lds;
// online softmax fp32; P via padded LDS [32][72] per wave.
__global__ __launch_bounds__(256) void flash_k(const __hip_bfloat16* __restrict__ q,
                                               const __hip_bfloat16* __restrict__ k,
                                               const __hip_bfloat16* __restrict__ vt,
                                               __hip_bfloat16* __restrict__ ao) {
  __shared__ char Ks[16384];
  __shared__ char VTs[16384];
  __shared__ char Ps[4 * 32 * 144];
  const int tid = threadIdx.x, lane = tid & 63, wid = tid >> 6;
  const int bx = blockIdx.x;
  const int qt = bx & 15, bh = bx >> 4, b = bh >> 4, h = bh & 15;
  const int l15 = lane & 15, l4 = lane >> 4;

  // Q fragments: rows qt*128 + wid*32 + mi*16 + l15, d-chunk kc*32 + l4*8
  short8 qf[2][4];
  const char* qB = (const char*)q;
#pragma unroll
  for (int mi = 0; mi < 2; ++mi)
#pragma unroll
    for (int kc = 0; kc < 4; ++kc) {
      const size_t off =
          ((size_t)(b * 2048 + qt * 128 + wid * 32 + mi * 16 + l15) * 2048 + h * 128 + kc * 32 + l4 * 8) * 2;
      qf[mi][kc] = *(const short8*)(qB + off);
    }

  f32x4 oacc[2][8] = {};
  float m_run[2][4], l_run[2][4];
#pragma unroll
  for (int mi = 0; mi < 2; ++mi)
#pragma unroll
    for (int r = 0; r < 4; ++r) { m_run[mi][r] = -1e30f; l_run[mi][r] = 0.f; }

  const int k_r = lane >> 4, k_c = lane & 15;  // K staging: 4 rows x 256B per 1KB chunk
  const int v_r = lane >> 3, v_c = lane & 7;   // VT staging: 8 rows x 128B per 1KB chunk
  const char* kbase = (const char*)k + ((size_t)(b * 2048) * 2048 + h * 128) * 2;
  const char* vtbase = (const char*)vt + ((size_t)bh * 128 * 2048) * 2;
  char* Psw = Ps + wid * (32 * 144);
  const float SC = 0.08838834764831845f;  // 1/sqrt(128)

  for (int t = 0; t < 32; ++t) {
    const int kv0 = t * 64;
#pragma unroll
    for (int c = 0; c < 4; ++c) {
      const int cid = wid * 4 + c;
      const int r = cid * 4 + k_r;
      gll16(kbase + (size_t)(kv0 + r) * 4096 + (k_c ^ (r & 7)) * 16, Ks + cid * 1024);
      const int rv = cid * 8 + v_r;
      gll16(vtbase + (size_t)rv * 4096 + (size_t)kv0 * 2 + (v_c ^ (rv & 7)) * 16, VTs + cid * 1024);
    }
    __syncthreads();

    // S = Q K^T (raw, scaled later)
    f32x4 sacc[2][4] = {};
#pragma unroll
    for (int kc = 0; kc < 4; ++kc) {
      short8 kf[4];
#pragma unroll
      for (int ni = 0; ni < 4; ++ni) {
        const int r = ni * 16 + l15;
        kf[ni] = *(const short8*)(Ks + r * 256 + (((kc * 4 + l4) ^ (r & 7)) * 16));
      }
#pragma unroll
      for (int mi = 0; mi < 2; ++mi)
#pragma unroll
        for (int ni = 0; ni < 4; ++ni)
          sacc[mi][ni] = __builtin_amdgcn_mfma_f32_16x16x32_bf16(qf[mi][kc], kf[ni], sacc[mi][ni], 0, 0, 0);
    }

    // online softmax: rows = mi*16 + l4*4 + r, cols across ni and 16 lanes
    float corr[2][4];
#pragma unroll
    for (int mi = 0; mi < 2; ++mi)
#pragma unroll
      for (int r = 0; r < 4; ++r) {
        float mx = fmaxf(fmaxf(sacc[mi][0][r], sacc[mi][1][r]),
                         fmaxf(sacc[mi][2][r], sacc[mi][3][r]));
        mx = fmaxf(mx, __shfl_xor(mx, 1));
        mx = fmaxf(mx, __shfl_xor(mx, 2));
        mx = fmaxf(mx, __shfl_xor(mx, 4));
        mx = fmaxf(mx, __shfl_xor(mx, 8));
        mx *= SC;
        const float mn = fmaxf(m_run[mi][r], mx);
        corr[mi][r] = __expf(m_run[mi][r] - mn);
        m_run[mi][r] = mn;
      }
#pragma unroll
    for (int mi = 0; mi < 2; ++mi)
#pragma unroll
      for (int r = 0; r < 4; ++r) {
        float rsum = 0.f;
#pragma unroll
        for (int ni = 0; ni < 4; ++ni) {
          const float pv = __expf(sacc[mi][ni][r] * SC - m_run[mi][r]);
          rsum += pv;
          *(__hip_bfloat16*)(Psw + (mi * 16 + l4 * 4 + r) * 144 + (ni * 16 + l15) * 2) =
              __float2bfloat16(pv);
        }
        rsum += __shfl_xor(rsum, 1);
        rsum += __shfl_xor(rsum, 2);
        rsum += __shfl_xor(rsum, 4);
        rsum += __shfl_xor(rsum, 8);
        l_run[mi][r] = l_run[mi][r] * corr[mi][r] + rsum;
      }
#pragma unroll
    for (int mi = 0; mi < 2; ++mi)
#pragma unroll
      for (int nd = 0; nd < 8; ++nd)
#pragma unroll
        for (int r = 0; r < 4; ++r) oacc[mi][nd][r] *= corr[mi][r];

    // O += P V  (A = P from LDS, B = V^T rows)
#pragma unroll
    for (int kc = 0; kc < 2; ++kc) {
      short8 pf[2];
#pragma unroll
      for (int mi = 0; mi < 2; ++mi)
        pf[mi] = *(const short8*)(Psw + (mi * 16 + l15) * 144 + kc * 64 + l4 * 16);
#pragma unroll
      for (int nd = 0; nd < 8; ++nd) {
        const int rvt = nd * 16 + l15;
        const short8 vf = *(const short8*)(VTs + rvt * 128 + (((kc * 4 + l4) ^ (rvt & 7)) * 16));
#pragma unroll
        for (int mi = 0; mi < 2; ++mi)
          oacc[mi][nd] = __builtin_amdgcn_mfma_f32_16x16x32_bf16(pf[mi], vf, oacc[mi][nd], 0, 0, 0);
      }
    }
    __syncthreads();
  }

  // epilogue: out rows = q, cols = h*128 + d
#pragma unroll
  for (int mi = 0; mi < 2; ++mi)
#pragma unroll
    for (int r = 0; r < 4; ++r) {
      const float inv = 1.f / l_run[mi][r];
      const int qrow = qt * 128 + wid * 32 + mi * 16 + l4 * 4 + r;
      const size_t rowoff = ((size_t)(b * 2048 + qrow)) * 2048 + h * 128;
#pragma unroll
      for (int nd = 0; nd < 8; ++nd)
        ao[rowoff + nd * 16 + l15] = __float2bfloat16(oacc[mi][nd][r] * inv);
    }
}

extern "C" void kernel_launch(void* const* d_in, const int* in_sizes, int n_in,
                              void* d_out, int out_size, void* d_ws, size_t ws_size,
                              hipStream_t stream) {
  const float* x  = (const float*)d_in[0];
  const float* Wq = (const float*)d_in[1];
  const float* Wk = (const float*)d_in[2];
  const float* Wv = (const float*)d_in[3];
  const float* Wo = (const float*)d_in[4];
  float* out = (float*)d_out;

  const size_t MK = (size_t)4096 * 2048;  // 8,388,608
  const size_t WN = (size_t)2048 * 2048;  // 4,194,304
  if (ws_size < (4 * MK + WN) * 2) return;  // need ~72MB

  __hip_bfloat16* ws  = (__hip_bfloat16*)d_ws;
  __hip_bfloat16* xb  = ws;             // also reused as attention output (aob)
  __hip_bfloat16* qb  = ws + MK;
  __hip_bfloat16* kb  = ws + 2 * MK;
  __hip_bfloat16* vtb = ws + 3 * MK;
  __hip_bfloat16* wsl = ws + 4 * MK;
  __hip_bfloat16* aob = xb;

  const dim3 gW((int)(WN / 4 / 256));
  const dim3 gX((int)(MK / 4 / 256));
  const dim3 gG(32, 16);  // M/128, N/128

  cast_f32_bf16<<<gX, 256, 0, stream>>>(x, xb, (int)(MK / 4));
  cast_f32_bf16<<<gW, 256, 0, stream>>>(Wq, wsl, (int)(WN / 4));
  gemm_bt<0><<<gG, 256, 0, stream>>>(xb, wsl, qb, 4096, 2048, 2048);
  cast_f32_bf16<<<gW, 256, 0, stream>>>(Wk, wsl, (int)(WN / 4));
  gemm_bt<0><<<gG, 256, 0, stream>>>(xb, wsl, kb, 4096, 2048, 2048);
  cast_f32_bf16<<<gW, 256, 0, stream>>>(Wv, wsl, (int)(WN / 4));
  gemm_bt<2><<<gG, 256, 0, stream>>>(xb, wsl, vtb, 4096, 2048, 2048);
  rope_k<<<32768, 256, 0, stream>>>(qb, kb);
  flash_k<<<512, 256, 0, stream>>>(qb, kb, vtb, aob);
  cast_f32_bf16<<<gW, 256, 0, stream>>>(Wo, wsl, (int)(WN / 4));
  gemm_bt<1><<<gG, 256, 0, stream>>>(aob, wsl, out, 4096, 2048, 2048);
}

// Round 3
// 369.913 us; speedup vs baseline: 1.1299x; 1.1299x over previous
//
#include <hip/hip_runtime.h>
#include <hip/hip_bf16.h>

// BaseTimeAttention: out = ((softmax(rope(xWq)·rope(xWk)^T/sqrt(d)))·(xWv)) @ Wo^T
// bf16 MFMA everywhere (no fp32 MFMA on CDNA4), fp32 accum + fp32 softmax.
// d_ws layout (bf16 elems): xb/aob(8.4M) | qb(8.4M) | kb(8.4M) | vtb(8.4M) | wslot(4.2M) = 72MB

typedef __attribute__((ext_vector_type(8))) short short8;
typedef __attribute__((ext_vector_type(4))) float f32x4;
typedef __attribute__((ext_vector_type(4))) unsigned short us4;
typedef __attribute__((ext_vector_type(4))) unsigned int u32x4;

__device__ __forceinline__ void gll16(const void* g, void* l) {
  __builtin_amdgcn_global_load_lds((const __attribute__((address_space(1))) void*)g,
                                   (__attribute__((address_space(3))) void*)l, 16, 0, 0);
}

__device__ __forceinline__ unsigned short f2bf(float f) {
  __hip_bfloat16 h = __float2bfloat16(f);
  return *reinterpret_cast<unsigned short*>(&h);
}

// pack two f32 -> one u32 of 2 bf16 (lo,hi) via HW instruction
__device__ __forceinline__ unsigned int cvtpk(float lo, float hi) {
  unsigned int r;
  asm("v_cvt_pk_bf16_f32 %0, %1, %2" : "=v"(r) : "v"(lo), "v"(hi));
  return r;
}

__global__ __launch_bounds__(256) void cast_f32_bf16(const float* __restrict__ in,
                                                     __hip_bfloat16* __restrict__ out, int n4) {
  int i = blockIdx.x * 256 + threadIdx.x;
  if (i >= n4) return;
  const float4 v = reinterpret_cast<const float4*>(in)[i];
  us4 o;
  o[0] = f2bf(v.x); o[1] = f2bf(v.y); o[2] = f2bf(v.z); o[3] = f2bf(v.w);
  *reinterpret_cast<us4*>(out + (size_t)i * 4) = o;
}

// C = A(MxK) * Bt(NxK)^T, 128x128 tile, BK=64, 4 waves (2x2 of 64x64).
// LDS tiles [128][64] bf16, XOR-swizzled: phys 16B-chunk = logical ^ (row&7).
// MODE 0: bf16 row-major. MODE 1: f32 row-major. MODE 2: V^T per (b,h) -> Cout[bh][d][kv].
template <int MODE>
__global__ __launch_bounds__(256) void gemm_bt(const __hip_bfloat16* __restrict__ A,
                                               const __hip_bfloat16* __restrict__ Bt,
                                               void* __restrict__ Cout,
                                               int M, int N, int K) {
  __shared__ char As[16384];
  __shared__ char Bs[16384];
  const int tid = threadIdx.x;
  const int lane = tid & 63, wid = tid >> 6;
  const int l15 = lane & 15, l4 = lane >> 4;
  const int row0 = blockIdx.x * 128, col0 = blockIdx.y * 128;
  const int wm = (wid >> 1) * 64, wn = (wid & 1) * 64;

  f32x4 acc[4][4] = {};

  const int rs = lane >> 3;       // row within 1KB staging chunk (8 rows x 128B)
  const int cs = lane & 7;        // 16B chunk within row
  const int cg = cs ^ rs;         // pre-swizzled global source chunk
  const char* Ab = (const char*)A;
  const char* Bb = (const char*)Bt;
  const size_t Kb = (size_t)K * 2;

  for (int k0 = 0; k0 < K; k0 += 64) {
#pragma unroll
    for (int c = 0; c < 4; ++c) {
      const int cid = wid * 4 + c;
      const int r = cid * 8 + rs;
      gll16(Ab + (size_t)(row0 + r) * Kb + (size_t)k0 * 2 + cg * 16, As + cid * 1024);
      gll16(Bb + (size_t)(col0 + r) * Kb + (size_t)k0 * 2 + cg * 16, Bs + cid * 1024);
    }
    __syncthreads();
#pragma unroll
    for (int kc = 0; kc < 2; ++kc) {
      short8 a[4], b[4];
#pragma unroll
      for (int i = 0; i < 4; ++i) {
        const int ra = wm + i * 16 + l15;
        a[i] = *(const short8*)(As + ra * 128 + (((kc * 4 + l4) ^ (ra & 7)) * 16));
        const int rb = wn + i * 16 + l15;
        b[i] = *(const short8*)(Bs + rb * 128 + (((kc * 4 + l4) ^ (rb & 7)) * 16));
      }
#pragma unroll
      for (int i = 0; i < 4; ++i)
#pragma unroll
        for (int j = 0; j < 4; ++j)
          acc[i][j] = __builtin_amdgcn_mfma_f32_16x16x32_bf16(a[i], b[j], acc[i][j], 0, 0, 0);
    }
    __syncthreads();
  }

  if (MODE == 2) {
    // C layout: col = lane&15, row = (lane>>4)*4 + reg -> 4 consecutive kv per lane: pack 8B.
    __hip_bfloat16* vt = (__hip_bfloat16*)Cout;
#pragma unroll
    for (int i = 0; i < 4; ++i) {
      const int gm = row0 + wm + i * 16 + l4 * 4;   // global row = b*2048 + kv
      const int bb = gm >> 11, kv = gm & 2047;
#pragma unroll
      for (int j = 0; j < 4; ++j) {
        const int gn = col0 + wn + j * 16 + l15;    // global col = h*128 + d
        const int h = gn >> 7, d = gn & 127;
        us4 o;
        o[0] = f2bf(acc[i][j][0]); o[1] = f2bf(acc[i][j][1]);
        o[2] = f2bf(acc[i][j][2]); o[3] = f2bf(acc[i][j][3]);
        *reinterpret_cast<us4*>(vt + ((size_t)((bb * 16 + h) * 128 + d) * 2048 + kv)) = o;
      }
    }
  } else {
#pragma unroll
    for (int i = 0; i < 4; ++i)
#pragma unroll
      for (int j = 0; j < 4; ++j) {
        const int gn = col0 + wn + j * 16 + l15;
#pragma unroll
        for (int r = 0; r < 4; ++r) {
          const int gm = row0 + wm + i * 16 + l4 * 4 + r;
          if (MODE == 0)
            ((__hip_bfloat16*)Cout)[(size_t)gm * N + gn] = __float2bfloat16(acc[i][j][r]);
          else
            ((float*)Cout)[(size_t)gm * N + gn] = acc[i][j][r];
        }
      }
  }
}

// RoPE in place on q and k. t -> (tensor, row, h, i); rotate (i, i+64) within each head.
__global__ __launch_bounds__(256) void rope_k(__hip_bfloat16* __restrict__ q,
                                              __hip_bfloat16* __restrict__ k) {
  const int tid = blockIdx.x * 256 + threadIdx.x;
  const int PT = 4096 * 16 * 64;
  __hip_bfloat16* p = (tid < PT) ? q : k;
  const int t = (tid < PT) ? tid : tid - PT;
  const int i = t & 63;
  const int h = (t >> 6) & 15;
  const int row = t >> 10;
  const int pos = row & 2047;
  const float invf = exp2f((float)i * -0.20762050593046f);  // 10000^(-i/64)
  const float fr = (float)pos * invf;
  float sv, cv;
  sincosf(fr, &sv, &cv);
  const size_t base = (size_t)row * 2048 + h * 128 + i;
  const float x1 = __bfloat162float(p[base]);
  const float x2 = __bfloat162float(p[base + 64]);
  p[base]      = __float2bfloat16(x1 * cv - x2 * sv);
  p[base + 64] = __float2bfloat16(x1 * sv + x2 * cv);
}

// Flash attention, swapped-operand form. grid.x = 512 (16 q-tiles x 32 bh).
// 4 waves x 32 q-rows, KV tile 64. Q in regs.
// T14 async-STAGE split: global->reg loads for tile t+1 issued at iter top (latency hidden
// under tile-t compute); after barrier, regs are ds_written (XOR-swizzled at the WRITE side)
// into a single 32KB K/VT buffer; second barrier publishes. Two barriers/tile — the sync
// skeleton proven race-free across graph replays in round 1.
// QK^T swapped: mfma(K,Q) -> S^T (lane holds q=l15's row) -> in-lane softmax,
// P packed to bf16 in-register (cvt_pk), PV swapped: mfma(V^T,P) -> O^T.
// kv permutation sigma(kc,l4,j) = kc*32 + (j>>2)*16 + l4*4 + (j&3) shared by P-frag & V-frag.
__global__ __launch_bounds__(256) void flash_k(const __hip_bfloat16* __restrict__ q,
                                               const __hip_bfloat16* __restrict__ k,
                                               const __hip_bfloat16* __restrict__ vt,
                                               __hip_bfloat16* __restrict__ ao) {
  __shared__ char Ks[16384];   // K tile [64][128] bf16, swizzled
  __shared__ char VTs[16384];  // V^T tile [128][64] bf16, swizzled
  const int tid = threadIdx.x, lane = tid & 63, wid = tid >> 6;
  const int bx = blockIdx.x;
  const int qt = bx & 15, bh = bx >> 4, b = bh >> 4, h = bh & 15;
  const int l15 = lane & 15, l4 = lane >> 4;

  // Q fragments (B-operand): rows qt*128 + wid*32 + mi*16 + l15, d-chunk kc*32 + l4*8
  short8 qf[2][4];
  const char* qB = (const char*)q;
#pragma unroll
  for (int mi = 0; mi < 2; ++mi)
#pragma unroll
    for (int kc = 0; kc < 4; ++kc) {
      const size_t off =
          ((size_t)(b * 2048 + qt * 128 + wid * 32 + mi * 16 + l15) * 2048 + h * 128 + kc * 32 + l4 * 8) * 2;
      qf[mi][kc] = *(const short8*)(qB + off);
    }

  f32x4 oacc[2][8] = {};
  float m2[2] = {-1e30f, -1e30f};
  float lr[2] = {0.f, 0.f};

  const char* kbase = (const char*)k + ((size_t)(b * 2048) * 2048 + h * 128) * 2;
  const char* vtbase = (const char*)vt + ((size_t)bh * 128 * 2048) * 2;
  const float SC = 0.08838834764831845f;  // 1/sqrt(128)

  // Reg-staging geometry. K chunk cid (1KB) = rows cid*4..+3 (256B each);
  // V chunk cid = rows cid*8..+7 (128B each). Wave wid owns chunks wid*4..wid*4+3.
  const int krow = lane >> 4, kcol = lane & 15;  // K: row-in-chunk, 16B col chunk (linear global)
  const int vrow = lane >> 3, vcol = lane & 7;   // V
  u32x4 kreg[4], vreg[4];
  int kaddr[4], vaddr[4];
#pragma unroll
  for (int c = 0; c < 4; ++c) {
    const int cid = wid * 4 + c;
    const int r = cid * 4 + krow;
    kaddr[c] = cid * 1024 + krow * 256 + ((kcol ^ (r & 7)) * 16);
    const int rv = cid * 8 + vrow;
    vaddr[c] = cid * 1024 + vrow * 128 + ((vcol ^ (rv & 7)) * 16);
  }

#define KVLOAD(T)                                                                             \
  {                                                                                           \
    const int kv0_ = (T)*64;                                                                  \
    _Pragma("unroll") for (int c_ = 0; c_ < 4; ++c_) {                                        \
      const int cid_ = wid * 4 + c_;                                                          \
      kreg[c_] = *(const u32x4*)(kbase + (size_t)(kv0_ + cid_ * 4 + krow) * 4096 + kcol * 16);\
      vreg[c_] = *(const u32x4*)(vtbase + (size_t)(cid_ * 8 + vrow) * 4096 +                  \
                                 (size_t)kv0_ * 2 + vcol * 16);                               \
    }                                                                                         \
  }
#define KVWRITE                                                                               \
  {                                                                                           \
    _Pragma("unroll") for (int c_ = 0; c_ < 4; ++c_) {                                        \
      *(u32x4*)(Ks + kaddr[c_]) = kreg[c_];                                                   \
      *(u32x4*)(VTs + vaddr[c_]) = vreg[c_];                                                  \
    }                                                                                         \
  }

  KVLOAD(0);
  KVWRITE;
  __syncthreads();

  for (int t = 0; t < 32; ++t) {
    if (t < 31) KVLOAD(t + 1);  // issue early; latency hides under tile-t compute

    // S^T = (Q K^T)^T : mfma(A=K rows, B=Q rows) -> C[kv][q], col=l15=q, row=l4*4+r=kv
    f32x4 sacc[2][4] = {};
#pragma unroll
    for (int kc = 0; kc < 4; ++kc) {
      short8 kf[4];
#pragma unroll
      for (int ni = 0; ni < 4; ++ni) {
        const int r = ni * 16 + l15;
        kf[ni] = *(const short8*)(Ks + r * 256 + (((kc * 4 + l4) ^ (r & 7)) * 16));
      }
#pragma unroll
      for (int mi = 0; mi < 2; ++mi)
#pragma unroll
        for (int ni = 0; ni < 4; ++ni)
          sacc[mi][ni] = __builtin_amdgcn_mfma_f32_16x16x32_bf16(kf[ni], qf[mi][kc], sacc[mi][ni], 0, 0, 0);
    }

    // online softmax: each lane owns q = mi*16+l15; its 16 values are kv = ni*16+l4*4+r.
    unsigned int W[2][4][2];
#pragma unroll
    for (int mi = 0; mi < 2; ++mi) {
      float t0 = fmaxf(fmaxf(sacc[mi][0][0], sacc[mi][0][1]), fmaxf(sacc[mi][0][2], sacc[mi][0][3]));
      float t1 = fmaxf(fmaxf(sacc[mi][1][0], sacc[mi][1][1]), fmaxf(sacc[mi][1][2], sacc[mi][1][3]));
      float t2 = fmaxf(fmaxf(sacc[mi][2][0], sacc[mi][2][1]), fmaxf(sacc[mi][2][2], sacc[mi][2][3]));
      float t3 = fmaxf(fmaxf(sacc[mi][3][0], sacc[mi][3][1]), fmaxf(sacc[mi][3][2], sacc[mi][3][3]));
      float mx = fmaxf(fmaxf(t0, t1), fmaxf(t2, t3));
      mx = fmaxf(mx, __shfl_xor(mx, 16));
      mx = fmaxf(mx, __shfl_xor(mx, 32));
      const float mnew = fmaxf(m2[mi], mx * SC);
      const float corr = __expf(m2[mi] - mnew);
      m2[mi] = mnew;
      float rs = 0.f;
#pragma unroll
      for (int ni = 0; ni < 4; ++ni) {
        float p0 = __expf(fmaf(sacc[mi][ni][0], SC, -mnew));
        float p1 = __expf(fmaf(sacc[mi][ni][1], SC, -mnew));
        float p2 = __expf(fmaf(sacc[mi][ni][2], SC, -mnew));
        float p3 = __expf(fmaf(sacc[mi][ni][3], SC, -mnew));
        rs += (p0 + p1) + (p2 + p3);
        W[mi][ni][0] = cvtpk(p0, p1);
        W[mi][ni][1] = cvtpk(p2, p3);
      }
      rs += __shfl_xor(rs, 16);
      rs += __shfl_xor(rs, 32);
      lr[mi] = lr[mi] * corr + rs;
#pragma unroll
      for (int nd = 0; nd < 8; ++nd)
#pragma unroll
        for (int r = 0; r < 4; ++r) oacc[mi][nd][r] *= corr;
    }

    // O^T += (V^T) P : mfma(A=V^T rows=d, B=P rows=q) -> C[d][q], col=l15=q, row=l4*4+r=d
#pragma unroll
    for (int kc = 0; kc < 2; ++kc) {
      union { u32x4 u; short8 s; } pfu[2];
#pragma unroll
      for (int mi = 0; mi < 2; ++mi) {
        pfu[mi].u[0] = W[mi][kc * 2][0];
        pfu[mi].u[1] = W[mi][kc * 2][1];
        pfu[mi].u[2] = W[mi][kc * 2 + 1][0];
        pfu[mi].u[3] = W[mi][kc * 2 + 1][1];
      }
#pragma unroll
      for (int nd = 0; nd < 8; ++nd) {
        const int rvt = nd * 16 + l15;
        union { unsigned long long d[2]; short8 s; } vfu;
        // sigma: elems 0-3 = cols kc*32 + l4*4 + 0..3 ; elems 4-7 = cols kc*32+16 + l4*4 + 0..3
        vfu.d[0] = *(const unsigned long long*)(
            VTs + rvt * 128 + (((kc * 4 + (l4 >> 1)) ^ (rvt & 7)) * 16) + (l4 & 1) * 8);
        vfu.d[1] = *(const unsigned long long*)(
            VTs + rvt * 128 + (((kc * 4 + 2 + (l4 >> 1)) ^ (rvt & 7)) * 16) + (l4 & 1) * 8);
#pragma unroll
        for (int mi = 0; mi < 2; ++mi)
          oacc[mi][nd] = __builtin_amdgcn_mfma_f32_16x16x32_bf16(vfu.s, pfu[mi].s, oacc[mi][nd], 0, 0, 0);
      }
    }

    __syncthreads();            // all waves' LDS reads of tile t complete
    if (t < 31) { KVWRITE; }    // regs (already landed during compute) -> LDS, swizzled
    __syncthreads();            // tile t+1 visible to all waves
  }

  // epilogue: O^T layout -> lane holds q = mi*16+l15, d = nd*16 + l4*4 + r (4 consecutive)
#pragma unroll
  for (int mi = 0; mi < 2; ++mi) {
    const float inv = 1.f / lr[mi];
    const int qrow = qt * 128 + wid * 32 + mi * 16 + l15;
    const size_t rowoff = ((size_t)(b * 2048 + qrow)) * 2048 + h * 128;
#pragma unroll
    for (int nd = 0; nd < 8; ++nd) {
      us4 o;
      o[0] = f2bf(oacc[mi][nd][0] * inv);
      o[1] = f2bf(oacc[mi][nd][1] * inv);
      o[2] = f2bf(oacc[mi][nd][2] * inv);
      o[3] = f2bf(oacc[mi][nd][3] * inv);
      *reinterpret_cast<us4*>(ao + rowoff + nd * 16 + l4 * 4) = o;
    }
  }
#undef KVLOAD
#undef KVWRITE
}

extern "C" void kernel_launch(void* const* d_in, const int* in_sizes, int n_in,
                              void* d_out, int out_size, void* d_ws, size_t ws_size,
                              hipStream_t stream) {
  const float* x  = (const float*)d_in[0];
  const float* Wq = (const float*)d_in[1];
  const float* Wk = (const float*)d_in[2];
  const float* Wv = (const float*)d_in[3];
  const float* Wo = (const float*)d_in[4];
  float* out = (float*)d_out;

  const size_t MK = (size_t)4096 * 2048;  // 8,388,608
  const size_t WN = (size_t)2048 * 2048;  // 4,194,304
  if (ws_size < (4 * MK + WN) * 2) return;  // need ~72MB

  __hip_bfloat16* ws  = (__hip_bfloat16*)d_ws;
  __hip_bfloat16* xb  = ws;             // also reused as attention output (aob)
  __hip_bfloat16* qb  = ws + MK;
  __hip_bfloat16* kb  = ws + 2 * MK;
  __hip_bfloat16* vtb = ws + 3 * MK;
  __hip_bfloat16* wsl = ws + 4 * MK;
  __hip_bfloat16* aob = xb;

  const dim3 gW((int)(WN / 4 / 256));
  const dim3 gX((int)(MK / 4 / 256));
  const dim3 gG(32, 16);  // M/128, N/128

  cast_f32_bf16<<<gX, 256, 0, stream>>>(x, xb, (int)(MK / 4));
  cast_f32_bf16<<<gW, 256, 0, stream>>>(Wq, wsl, (int)(WN / 4));
  gemm_bt<0><<<gG, 256, 0, stream>>>(xb, wsl, qb, 4096, 2048, 2048);
  cast_f32_bf16<<<gW, 256, 0, stream>>>(Wk, wsl, (int)(WN / 4));
  gemm_bt<0><<<gG, 256, 0, stream>>>(xb, wsl, kb, 4096, 2048, 2048);
  cast_f32_bf16<<<gW, 256, 0, stream>>>(Wv, wsl, (int)(WN / 4));
  gemm_bt<2><<<gG, 256, 0, stream>>>(xb, wsl, vtb, 4096, 2048, 2048);
  rope_k<<<32768, 256, 0, stream>>>(qb, kb);
  flash_k<<<512, 256, 0, stream>>>(qb, kb, vtb, aob);
  cast_f32_bf16<<<gW, 256, 0, stream>>>(Wo, wsl, (int)(WN / 4));
  gemm_bt<1><<<gG, 256, 0, stream>>>(aob, wsl, out, 4096, 2048, 2048);
}

// Round 4
// 365.349 us; speedup vs baseline: 1.1440x; 1.0125x over previous
//
#include <hip/hip_runtime.h>
#include <hip/hip_bf16.h>

// BaseTimeAttention: out = ((softmax(rope(xWq)·rope(xWk)^T/sqrt(d)))·(xWv)) @ Wo^T
// bf16 MFMA everywhere (no fp32 MFMA on CDNA4), fp32 accum + fp32 softmax (exp2 domain).
// d_ws layout (bf16 elems): xb/aob(8.4M) | qb(8.4M) | kb(8.4M) | vtb(8.4M) | wslot(4.2M) = 72MB

typedef __attribute__((ext_vector_type(8))) short short8;
typedef __attribute__((ext_vector_type(4))) float f32x4;
typedef __attribute__((ext_vector_type(4))) unsigned short us4;
typedef __attribute__((ext_vector_type(4))) unsigned int u32x4;

__device__ __forceinline__ void gll16(const void* g, void* l) {
  __builtin_amdgcn_global_load_lds((const __attribute__((address_space(1))) void*)g,
                                   (__attribute__((address_space(3))) void*)l, 16, 0, 0);
}

__device__ __forceinline__ unsigned short f2bf(float f) {
  __hip_bfloat16 h = __float2bfloat16(f);
  return *reinterpret_cast<unsigned short*>(&h);
}

__device__ __forceinline__ float bf2f(short s) {
  union { unsigned int u; float f; } c;
  c.u = ((unsigned int)(unsigned short)s) << 16;
  return c.f;
}

// pack two f32 -> one u32 of 2 bf16 (lo,hi) via HW instruction
__device__ __forceinline__ unsigned int cvtpk(float lo, float hi) {
  unsigned int r;
  asm("v_cvt_pk_bf16_f32 %0, %1, %2" : "=v"(r) : "v"(lo), "v"(hi));
  return r;
}

__global__ __launch_bounds__(256) void cast_f32_bf16(const float* __restrict__ in,
                                                     __hip_bfloat16* __restrict__ out, int n4) {
  int i = blockIdx.x * 256 + threadIdx.x;
  if (i >= n4) return;
  const float4 v = reinterpret_cast<const float4*>(in)[i];
  us4 o;
  o[0] = f2bf(v.x); o[1] = f2bf(v.y); o[2] = f2bf(v.z); o[3] = f2bf(v.w);
  *reinterpret_cast<us4*>(out + (size_t)i * 4) = o;
}

// C = A(MxK) * Bt(NxK)^T, 128x128 tile, BK=64, 4 waves (2x2 of 64x64).
// LDS tiles [128][64] bf16, XOR-swizzled: phys 16B-chunk = logical ^ (row&7).
// MODE 0: bf16 row-major. MODE 1: f32 row-major. MODE 2: V^T per (b,h) -> Cout[bh][d][kv].
template <int MODE>
__global__ __launch_bounds__(256) void gemm_bt(const __hip_bfloat16* __restrict__ A,
                                               const __hip_bfloat16* __restrict__ Bt,
                                               void* __restrict__ Cout,
                                               int M, int N, int K) {
  __shared__ char As[16384];
  __shared__ char Bs[16384];
  const int tid = threadIdx.x;
  const int lane = tid & 63, wid = tid >> 6;
  const int l15 = lane & 15, l4 = lane >> 4;
  const int row0 = blockIdx.x * 128, col0 = blockIdx.y * 128;
  const int wm = (wid >> 1) * 64, wn = (wid & 1) * 64;

  f32x4 acc[4][4] = {};

  const int rs = lane >> 3;       // row within 1KB staging chunk (8 rows x 128B)
  const int cs = lane & 7;        // 16B chunk within row
  const int cg = cs ^ rs;         // pre-swizzled global source chunk
  const char* Ab = (const char*)A;
  const char* Bb = (const char*)Bt;
  const size_t Kb = (size_t)K * 2;

  for (int k0 = 0; k0 < K; k0 += 64) {
#pragma unroll
    for (int c = 0; c < 4; ++c) {
      const int cid = wid * 4 + c;
      const int r = cid * 8 + rs;
      gll16(Ab + (size_t)(row0 + r) * Kb + (size_t)k0 * 2 + cg * 16, As + cid * 1024);
      gll16(Bb + (size_t)(col0 + r) * Kb + (size_t)k0 * 2 + cg * 16, Bs + cid * 1024);
    }
    __syncthreads();
#pragma unroll
    for (int kc = 0; kc < 2; ++kc) {
      short8 a[4], b[4];
#pragma unroll
      for (int i = 0; i < 4; ++i) {
        const int ra = wm + i * 16 + l15;
        a[i] = *(const short8*)(As + ra * 128 + (((kc * 4 + l4) ^ (ra & 7)) * 16));
        const int rb = wn + i * 16 + l15;
        b[i] = *(const short8*)(Bs + rb * 128 + (((kc * 4 + l4) ^ (rb & 7)) * 16));
      }
#pragma unroll
      for (int i = 0; i < 4; ++i)
#pragma unroll
        for (int j = 0; j < 4; ++j)
          acc[i][j] = __builtin_amdgcn_mfma_f32_16x16x32_bf16(a[i], b[j], acc[i][j], 0, 0, 0);
    }
    __syncthreads();
  }

  if (MODE == 2) {
    // C layout: col = lane&15, row = (lane>>4)*4 + reg -> 4 consecutive kv per lane: pack 8B.
    __hip_bfloat16* vt = (__hip_bfloat16*)Cout;
#pragma unroll
    for (int i = 0; i < 4; ++i) {
      const int gm = row0 + wm + i * 16 + l4 * 4;   // global row = b*2048 + kv
      const int bb = gm >> 11, kv = gm & 2047;
#pragma unroll
      for (int j = 0; j < 4; ++j) {
        const int gn = col0 + wn + j * 16 + l15;    // global col = h*128 + d
        const int h = gn >> 7, d = gn & 127;
        us4 o;
        o[0] = f2bf(acc[i][j][0]); o[1] = f2bf(acc[i][j][1]);
        o[2] = f2bf(acc[i][j][2]); o[3] = f2bf(acc[i][j][3]);
        *reinterpret_cast<us4*>(vt + ((size_t)((bb * 16 + h) * 128 + d) * 2048 + kv)) = o;
      }
    }
  } else {
#pragma unroll
    for (int i = 0; i < 4; ++i)
#pragma unroll
      for (int j = 0; j < 4; ++j) {
        const int gn = col0 + wn + j * 16 + l15;
#pragma unroll
        for (int r = 0; r < 4; ++r) {
          const int gm = row0 + wm + i * 16 + l4 * 4 + r;
          if (MODE == 0)
            ((__hip_bfloat16*)Cout)[(size_t)gm * N + gn] = __float2bfloat16(acc[i][j][r]);
          else
            ((float*)Cout)[(size_t)gm * N + gn] = acc[i][j][r];
        }
      }
  }
}

// RoPE in place on q and k, vectorized 8-wide. 2^20 threads; thread handles 8 consecutive i
// of one (tensor,row,head): two 16B loads (i, i+64), two 16B stores.
__global__ __launch_bounds__(256) void rope_k(__hip_bfloat16* __restrict__ q,
                                              __hip_bfloat16* __restrict__ k) {
  const int tid = blockIdx.x * 256 + threadIdx.x;
  const int i8 = tid & 7;
  const int h = (tid >> 3) & 15;
  const int row = (tid >> 7) & 4095;
  __hip_bfloat16* p = (tid >> 19) ? k : q;
  const int pos = row & 2047;
  const size_t base = (size_t)row * 2048 + h * 128 + i8 * 8;
  const short8 v1 = *reinterpret_cast<const short8*>(p + base);
  const short8 v2 = *reinterpret_cast<const short8*>(p + base + 64);
  short8 o1, o2;
#pragma unroll
  for (int j = 0; j < 8; ++j) {
    const int i = i8 * 8 + j;
    const float invf = exp2f((float)i * -0.20762050593046f);  // 10000^(-i/64)
    const float fr = (float)pos * invf;
    float sv, cv;
    sincosf(fr, &sv, &cv);
    const float x1 = bf2f(v1[j]), x2 = bf2f(v2[j]);
    o1[j] = (short)f2bf(x1 * cv - x2 * sv);
    o2[j] = (short)f2bf(x1 * sv + x2 * cv);
  }
  *reinterpret_cast<short8*>(p + base) = o1;
  *reinterpret_cast<short8*>(p + base + 64) = o2;
}

// Flash attention, swapped-operand form. grid.x = 1024 (32 q-tiles x 32 bh).
// 4 waves x 16 q-rows (QBLK=64), KV tile 64 -> 4 blocks/CU resident for latency hiding.
// Q in regs. T14 async-STAGE split: global->reg loads for tile t+1 at iter top; after
// barrier, swizzled ds_write into single 32KB K/VT buffer; second barrier publishes.
// QK^T swapped: mfma(K,Q) -> S^T (lane holds q=l15's row) -> in-lane softmax in exp2 domain,
// T13 defer-rescale (THR=8 log2), P packed bf16 in-register (cvt_pk), PV swapped -> O^T.
// kv permutation sigma(kc,l4,j) = kc*32 + (j>>2)*16 + l4*4 + (j&3) shared by P-frag & V-frag.
__global__ __launch_bounds__(256) void flash_k(const __hip_bfloat16* __restrict__ q,
                                               const __hip_bfloat16* __restrict__ k,
                                               const __hip_bfloat16* __restrict__ vt,
                                               __hip_bfloat16* __restrict__ ao) {
  __shared__ char Ks[16384];   // K tile [64][128] bf16, swizzled
  __shared__ char VTs[16384];  // V^T tile [128][64] bf16, swizzled
  const int tid = threadIdx.x, lane = tid & 63, wid = tid >> 6;
  const int bx = blockIdx.x;
  const int qt = bx & 31, bh = bx >> 5, b = bh >> 4, h = bh & 15;
  const int l15 = lane & 15, l4 = lane >> 4;

  // Q fragments (B-operand): rows qt*64 + wid*16 + l15, d-chunk kc*32 + l4*8
  short8 qf[4];
  const char* qB = (const char*)q;
#pragma unroll
  for (int kc = 0; kc < 4; ++kc) {
    const size_t off =
        ((size_t)(b * 2048 + qt * 64 + wid * 16 + l15) * 2048 + h * 128 + kc * 32 + l4 * 8) * 2;
    qf[kc] = *(const short8*)(qB + off);
  }

  f32x4 oacc[8] = {};
  float m2 = -1e30f;   // running max in log2 units
  float lr = 0.f;      // running denom (exp2 domain)

  const char* kbase = (const char*)k + ((size_t)(b * 2048) * 2048 + h * 128) * 2;
  const char* vtbase = (const char*)vt + ((size_t)bh * 128 * 2048) * 2;
  const float SC2 = 0.1275224187f;  // (1/sqrt(128)) * log2(e)

  // Reg-staging geometry. K chunk cid (1KB) = rows cid*4..+3 (256B each);
  // V chunk cid = rows cid*8..+7 (128B each). Wave wid owns chunks wid*4..wid*4+3.
  const int krow = lane >> 4, kcol = lane & 15;
  const int vrow = lane >> 3, vcol = lane & 7;
  u32x4 kreg[4], vreg[4];
  int kaddr[4], vaddr[4];
#pragma unroll
  for (int c = 0; c < 4; ++c) {
    const int cid = wid * 4 + c;
    const int r = cid * 4 + krow;
    kaddr[c] = cid * 1024 + krow * 256 + ((kcol ^ (r & 7)) * 16);
    const int rv = cid * 8 + vrow;
    vaddr[c] = cid * 1024 + vrow * 128 + ((vcol ^ (rv & 7)) * 16);
  }

#define KVLOAD(T)                                                                             \
  {                                                                                           \
    const int kv0_ = (T)*64;                                                                  \
    _Pragma("unroll") for (int c_ = 0; c_ < 4; ++c_) {                                        \
      const int cid_ = wid * 4 + c_;                                                          \
      kreg[c_] = *(const u32x4*)(kbase + (size_t)(kv0_ + cid_ * 4 + krow) * 4096 + kcol * 16);\
      vreg[c_] = *(const u32x4*)(vtbase + (size_t)(cid_ * 8 + vrow) * 4096 +                  \
                                 (size_t)kv0_ * 2 + vcol * 16);                               \
    }                                                                                         \
  }
#define KVWRITE                                                                               \
  {                                                                                           \
    _Pragma("unroll") for (int c_ = 0; c_ < 4; ++c_) {                                        \
      *(u32x4*)(Ks + kaddr[c_]) = kreg[c_];                                                   \
      *(u32x4*)(VTs + vaddr[c_]) = vreg[c_];                                                  \
    }                                                                                         \
  }

  KVLOAD(0);
  KVWRITE;
  __syncthreads();

  for (int t = 0; t < 32; ++t) {
    if (t < 31) KVLOAD(t + 1);  // issue early; latency hides under tile-t compute

    // S^T = (Q K^T)^T : mfma(A=K rows, B=Q rows) -> C[kv][q], col=l15=q, row=l4*4+r=kv
    f32x4 sacc[4] = {};
#pragma unroll
    for (int kc = 0; kc < 4; ++kc) {
      short8 kf[4];
#pragma unroll
      for (int ni = 0; ni < 4; ++ni) {
        const int r = ni * 16 + l15;
        kf[ni] = *(const short8*)(Ks + r * 256 + (((kc * 4 + l4) ^ (r & 7)) * 16));
      }
#pragma unroll
      for (int ni = 0; ni < 4; ++ni)
        sacc[ni] = __builtin_amdgcn_mfma_f32_16x16x32_bf16(kf[ni], qf[kc], sacc[ni], 0, 0, 0);
    }

    // online softmax (exp2 domain): lane owns q = l15; 16 values are kv = ni*16+l4*4+r.
    {
      float t0 = fmaxf(fmaxf(sacc[0][0], sacc[0][1]), fmaxf(sacc[0][2], sacc[0][3]));
      float t1 = fmaxf(fmaxf(sacc[1][0], sacc[1][1]), fmaxf(sacc[1][2], sacc[1][3]));
      float t2 = fmaxf(fmaxf(sacc[2][0], sacc[2][1]), fmaxf(sacc[2][2], sacc[2][3]));
      float t3 = fmaxf(fmaxf(sacc[3][0], sacc[3][1]), fmaxf(sacc[3][2], sacc[3][3]));
      float mx = fmaxf(fmaxf(t0, t1), fmaxf(t2, t3));
      mx = fmaxf(mx, __shfl_xor(mx, 16));
      mx = fmaxf(mx, __shfl_xor(mx, 32));
      const float pm = mx * SC2;
      // T13 defer-rescale: only rescale when some row's max grew past THR=8 (log2 units).
      if (!__all(pm - m2 <= 8.0f)) {
        const float mnew = fmaxf(m2, pm);
        const float corr = exp2f(m2 - mnew);
        m2 = mnew;
        lr *= corr;
#pragma unroll
        for (int nd = 0; nd < 8; ++nd)
#pragma unroll
          for (int r = 0; r < 4; ++r) oacc[nd][r] *= corr;
      }
    }
    unsigned int W[4][2];
    {
      float rs = 0.f;
#pragma unroll
      for (int ni = 0; ni < 4; ++ni) {
        float p0 = exp2f(fmaf(sacc[ni][0], SC2, -m2));
        float p1 = exp2f(fmaf(sacc[ni][1], SC2, -m2));
        float p2 = exp2f(fmaf(sacc[ni][2], SC2, -m2));
        float p3 = exp2f(fmaf(sacc[ni][3], SC2, -m2));
        rs += (p0 + p1) + (p2 + p3);
        W[ni][0] = cvtpk(p0, p1);
        W[ni][1] = cvtpk(p2, p3);
      }
      rs += __shfl_xor(rs, 16);
      rs += __shfl_xor(rs, 32);
      lr += rs;
    }

    // O^T += (V^T) P : mfma(A=V^T rows=d, B=P rows=q) -> C[d][q], col=l15=q, row=l4*4+r=d
#pragma unroll
    for (int kc = 0; kc < 2; ++kc) {
      union { u32x4 u; short8 s; } pfu;
      pfu.u[0] = W[kc * 2][0];
      pfu.u[1] = W[kc * 2][1];
      pfu.u[2] = W[kc * 2 + 1][0];
      pfu.u[3] = W[kc * 2 + 1][1];
#pragma unroll
      for (int nd = 0; nd < 8; ++nd) {
        const int rvt = nd * 16 + l15;
        union { unsigned long long d[2]; short8 s; } vfu;
        // sigma: elems 0-3 = cols kc*32 + l4*4 + 0..3 ; elems 4-7 = cols kc*32+16 + l4*4 + 0..3
        vfu.d[0] = *(const unsigned long long*)(
            VTs + rvt * 128 + (((kc * 4 + (l4 >> 1)) ^ (rvt & 7)) * 16) + (l4 & 1) * 8);
        vfu.d[1] = *(const unsigned long long*)(
            VTs + rvt * 128 + (((kc * 4 + 2 + (l4 >> 1)) ^ (rvt & 7)) * 16) + (l4 & 1) * 8);
        oacc[nd] = __builtin_amdgcn_mfma_f32_16x16x32_bf16(vfu.s, pfu.s, oacc[nd], 0, 0, 0);
      }
    }

    __syncthreads();            // all waves' LDS reads of tile t complete
    if (t < 31) { KVWRITE; }    // regs (already landed during compute) -> LDS, swizzled
    __syncthreads();            // tile t+1 visible to all waves
  }

  // epilogue: O^T layout -> lane holds q = l15, d = nd*16 + l4*4 + r (4 consecutive)
  {
    const float inv = 1.f / lr;
    const int qrow = qt * 64 + wid * 16 + l15;
    const size_t rowoff = ((size_t)(b * 2048 + qrow)) * 2048 + h * 128;
#pragma unroll
    for (int nd = 0; nd < 8; ++nd) {
      us4 o;
      o[0] = f2bf(oacc[nd][0] * inv);
      o[1] = f2bf(oacc[nd][1] * inv);
      o[2] = f2bf(oacc[nd][2] * inv);
      o[3] = f2bf(oacc[nd][3] * inv);
      *reinterpret_cast<us4*>(ao + rowoff + nd * 16 + l4 * 4) = o;
    }
  }
#undef KVLOAD
#undef KVWRITE
}

extern "C" void kernel_launch(void* const* d_in, const int* in_sizes, int n_in,
                              void* d_out, int out_size, void* d_ws, size_t ws_size,
                              hipStream_t stream) {
  const float* x  = (const float*)d_in[0];
  const float* Wq = (const float*)d_in[1];
  const float* Wk = (const float*)d_in[2];
  const float* Wv = (const float*)d_in[3];
  const float* Wo = (const float*)d_in[4];
  float* out = (float*)d_out;

  const size_t MK = (size_t)4096 * 2048;  // 8,388,608
  const size_t WN = (size_t)2048 * 2048;  // 4,194,304
  if (ws_size < (4 * MK + WN) * 2) return;  // need ~72MB

  __hip_bfloat16* ws  = (__hip_bfloat16*)d_ws;
  __hip_bfloat16* xb  = ws;             // also reused as attention output (aob)
  __hip_bfloat16* qb  = ws + MK;
  __hip_bfloat16* kb  = ws + 2 * MK;
  __hip_bfloat16* vtb = ws + 3 * MK;
  __hip_bfloat16* wsl = ws + 4 * MK;
  __hip_bfloat16* aob = xb;

  const dim3 gW((int)(WN / 4 / 256));
  const dim3 gX((int)(MK / 4 / 256));
  const dim3 gG(32, 16);  // M/128, N/128

  cast_f32_bf16<<<gX, 256, 0, stream>>>(x, xb, (int)(MK / 4));
  cast_f32_bf16<<<gW, 256, 0, stream>>>(Wq, wsl, (int)(WN / 4));
  gemm_bt<0><<<gG, 256, 0, stream>>>(xb, wsl, qb, 4096, 2048, 2048);
  cast_f32_bf16<<<gW, 256, 0, stream>>>(Wk, wsl, (int)(WN / 4));
  gemm_bt<0><<<gG, 256, 0, stream>>>(xb, wsl, kb, 4096, 2048, 2048);
  cast_f32_bf16<<<gW, 256, 0, stream>>>(Wv, wsl, (int)(WN / 4));
  gemm_bt<2><<<gG, 256, 0, stream>>>(xb, wsl, vtb, 4096, 2048, 2048);
  rope_k<<<4096, 256, 0, stream>>>(qb, kb);
  flash_k<<<1024, 256, 0, stream>>>(qb, kb, vtb, aob);
  cast_f32_bf16<<<gW, 256, 0, stream>>>(Wo, wsl, (int)(WN / 4));
  gemm_bt<1><<<gG, 256, 0, stream>>>(aob, wsl, out, 4096, 2048, 2048);
}